// Round 1
// baseline (1319.491 us; speedup 1.0000x reference)
//
#include <hip/hip_runtime.h>

// ---------------------------------------------------------------------------
// 3-layer GAT (heads=1) forward. Sizes fixed by the problem:
//   N=100000 nodes, E=1600000 edges, Ep=E+N (self loops), G=128 graphs
//   ND=16, ED=2, H=32
// Strategy: build CSR over dst on-device (atomics+scan), then per-layer:
//   hproj (h = x@W, a_src = h@a_s, a_dst = h@a_d)
//   edgep (p_e = exp(leaky_relu(a_src[s]+a_dst[d]+a_edge)))   [no max-shift;
//          logits are ~0.1 magnitude so this is numerically safe]
//   agg   (per dst node: sum p over row, out_j = (sum p_e*h[s][j])/sum + b_j)
// Pool: batch is sorted -> binary-search boundaries, one block per graph.
// ---------------------------------------------------------------------------

__global__ void k_node_enc(const float* __restrict__ nf, const float* __restrict__ W,
                           const float* __restrict__ b, float* __restrict__ x, int n) {
    int gid = blockIdx.x * 256 + threadIdx.x;
    if (gid >= n * 16) return;
    int node = gid >> 4, j = gid & 15;
    const float* xr = nf + node * 9;
    float acc = b[j];
#pragma unroll
    for (int k = 0; k < 9; ++k) acc += xr[k] * W[k * 16 + j];
    x[gid] = acc;
}

__global__ void k_edge_enc(const float* __restrict__ ea, const float* __restrict__ W,
                           const float* __restrict__ b, float* __restrict__ ef,
                           float* __restrict__ colsum, int e) {
    __shared__ float s0[256], s1[256];
    int gid = blockIdx.x * 256 + threadIdx.x;
    float f0 = 0.f, f1 = 0.f;
    if (gid < e) {
        const float* r = ea + (size_t)gid * 3;
        float a0 = r[0], a1 = r[1], a2 = r[2];
        f0 = a0 * W[0] + a1 * W[2] + a2 * W[4] + b[0];
        f1 = a0 * W[1] + a1 * W[3] + a2 * W[5] + b[1];
        ef[(size_t)gid * 2 + 0] = f0;
        ef[(size_t)gid * 2 + 1] = f1;
    }
    s0[threadIdx.x] = f0; s1[threadIdx.x] = f1;
    __syncthreads();
    for (int off = 128; off > 0; off >>= 1) {
        if (threadIdx.x < off) {
            s0[threadIdx.x] += s0[threadIdx.x + off];
            s1[threadIdx.x] += s1[threadIdx.x + off];
        }
        __syncthreads();
    }
    if (threadIdx.x == 0) { atomicAdd(colsum + 0, s0[0]); atomicAdd(colsum + 1, s1[0]); }
}

__global__ void k_deg(const int* __restrict__ dstE, int* __restrict__ deg, int e, int n) {
    int gid = blockIdx.x * 256 + threadIdx.x;
    if (gid >= e + n) return;
    int d = (gid < e) ? dstE[gid] : gid - e;
    atomicAdd(deg + d, 1);
}

__global__ void k_scan1(const int* __restrict__ deg, int* __restrict__ rp,
                        int* __restrict__ aux, int n) {
    __shared__ int s[256];
    int t = threadIdx.x, i = blockIdx.x * 256 + t;
    int v = (i < n) ? deg[i] : 0;
    s[t] = v; __syncthreads();
    for (int o = 1; o < 256; o <<= 1) {
        int x = (t >= o) ? s[t - o] : 0;
        __syncthreads();
        s[t] += x;
        __syncthreads();
    }
    if (i < n) rp[i] = s[t] - v;          // chunk-exclusive
    if (t == 255) aux[blockIdx.x] = s[255]; // chunk total
}

__global__ void k_scan2(int* __restrict__ aux, int nb) {
    __shared__ int s[512];
    int t = threadIdx.x;
    int v = (t < nb) ? aux[t] : 0;
    s[t] = v; __syncthreads();
    for (int o = 1; o < 512; o <<= 1) {
        int x = (t >= o) ? s[t - o] : 0;
        __syncthreads();
        s[t] += x;
        __syncthreads();
    }
    if (t < nb) aux[t] = s[t] - v;        // exclusive block offsets
}

__global__ void k_scan3(int* __restrict__ rp, const int* __restrict__ aux,
                        int* __restrict__ cursor, int n, int ep) {
    int i = blockIdx.x * 256 + threadIdx.x;
    if (i < n) {
        int v = rp[i] + aux[blockIdx.x];
        rp[i] = v;
        cursor[i] = v;
    }
    if (i == 0) rp[n] = ep;
}

__global__ void k_scatter(const int* __restrict__ dstE, int* __restrict__ cursor,
                          int* __restrict__ sorted, int e, int n) {
    int gid = blockIdx.x * 256 + threadIdx.x;
    if (gid >= e + n) return;
    int d = (gid < e) ? dstE[gid] : gid - e;
    int pos = atomicAdd(cursor + d, 1);
    sorted[pos] = gid;
}

// consts layout (floats): [0..5]=c[l][k] (k fast), [6..8]=loop a_edge per layer,
// [12..13]=ef column sums (atomically accumulated, memset 0 first)
__global__ void k_consts(const float* __restrict__ We0, const float* __restrict__ ae0,
                         const float* __restrict__ We1, const float* __restrict__ ae1,
                         const float* __restrict__ We2, const float* __restrict__ ae2,
                         float* __restrict__ consts, float einv) {
    if (threadIdx.x != 0 || blockIdx.x != 0) return;
    const float* We[3] = {We0, We1, We2};
    const float* ae[3] = {ae0, ae1, ae2};
    float m0 = consts[12] * einv, m1 = consts[13] * einv;
    for (int l = 0; l < 3; ++l) {
        float c0 = 0.f, c1 = 0.f;
        for (int j = 0; j < 32; ++j) {
            c0 += We[l][j] * ae[l][j];
            c1 += We[l][32 + j] * ae[l][j];
        }
        consts[l * 2 + 0] = c0;
        consts[l * 2 + 1] = c1;
        consts[6 + l] = m0 * c0 + m1 * c1;
    }
}

template <int K>
__global__ void k_hproj(const float* __restrict__ x, const float* __restrict__ W,
                        const float* __restrict__ as_, const float* __restrict__ ad_,
                        float* __restrict__ h, float* __restrict__ asrc,
                        float* __restrict__ adst, int n) {
    __shared__ float sW[K * 32];
    for (int i = threadIdx.x; i < K * 32; i += 256) sW[i] = W[i];
    __syncthreads();
    int node = blockIdx.x * 8 + (threadIdx.x >> 5);
    int j = threadIdx.x & 31;
    if (node >= n) return;
    const float* xr = x + (size_t)node * K;
    float acc = 0.f;
#pragma unroll
    for (int k = 0; k < K; ++k) acc += xr[k] * sW[k * 32 + j];
    h[(size_t)node * 32 + j] = acc;
    float r1 = acc * as_[j], r2 = acc * ad_[j];
    for (int off = 16; off > 0; off >>= 1) {
        r1 += __shfl_xor(r1, off);
        r2 += __shfl_xor(r2, off);
    }
    if (j == 0) { asrc[node] = r1; adst[node] = r2; }
}

__global__ void k_edgep(const int* __restrict__ ei0, const int* __restrict__ ei1,
                        const float* __restrict__ ef, const float* __restrict__ asrc,
                        const float* __restrict__ adst, const float* __restrict__ consts,
                        float* __restrict__ p, int e, int n, int layer) {
    int gid = blockIdx.x * 256 + threadIdx.x;
    if (gid >= e + n) return;
    float c0 = consts[layer * 2], c1 = consts[layer * 2 + 1], lc = consts[6 + layer];
    int s, d; float ae;
    if (gid < e) {
        s = ei0[gid]; d = ei1[gid];
        ae = ef[(size_t)gid * 2] * c0 + ef[(size_t)gid * 2 + 1] * c1;
    } else {
        s = d = gid - e; ae = lc;
    }
    float lg = asrc[s] + adst[d] + ae;
    lg = lg > 0.f ? lg : 0.2f * lg;
    p[gid] = __expf(lg);
}

__global__ void k_agg(const int* __restrict__ ei0, const int* __restrict__ rp,
                      const int* __restrict__ sorted, const float* __restrict__ p,
                      const float* __restrict__ h, const float* __restrict__ bb,
                      float* __restrict__ xout, int e, int n) {
    int node = blockIdx.x * 8 + (threadIdx.x >> 5);
    int j = threadIdx.x & 31;
    if (node >= n) return;
    int r0 = rp[node], r1 = rp[node + 1];
    float sum = 0.f;
    for (int i = r0 + j; i < r1; i += 32) sum += p[sorted[i]];
    for (int off = 16; off > 0; off >>= 1) sum += __shfl_xor(sum, off);
    float inv = 1.f / (sum + 1e-16f);
    float acc = 0.f;
    for (int i = r0; i < r1; ++i) {
        int eid = sorted[i];
        float pe = p[eid];
        int s = (eid < e) ? ei0[eid] : eid - e;
        acc += pe * h[(size_t)s * 32 + j];
    }
    xout[(size_t)node * 32 + j] = acc * inv + bb[j];
}

__global__ void k_bounds(const int* __restrict__ batch, int* __restrict__ bounds,
                         int n, int g) {
    int t = blockIdx.x * 256 + threadIdx.x;
    if (t > g) return;
    if (t == g) { bounds[g] = n; return; }
    int lo = 0, hi = n;
    while (lo < hi) {
        int mid = (lo + hi) >> 1;
        if (batch[mid] < t) lo = mid + 1; else hi = mid;
    }
    bounds[t] = lo;
}

__global__ void k_pool(const float* __restrict__ x1, const float* __restrict__ x2,
                       const float* __restrict__ x3, const int* __restrict__ bounds,
                       const float* __restrict__ Wl3, const float* __restrict__ bl3,
                       float* __restrict__ out) {
    __shared__ float cs[96];
    int g = blockIdx.x, t = threadIdx.x;
    int s0 = bounds[g], s1 = bounds[g + 1];
    if (t < 96) {
        const float* X = (t < 32) ? x1 : (t < 64) ? x2 : x3;
        int col = t & 31;
        float acc = 0.f;
        for (int nid = s0; nid < s1; ++nid) acc += X[(size_t)nid * 32 + col];
        cs[t] = acc;
    }
    __syncthreads();
    if (t == 0) {
        float dot = 0.f;
        for (int jj = 0; jj < 96; ++jj) dot += cs[jj] * Wl3[jj];
        float cnt = (float)(s1 - s0);
        if (cnt < 1.f) cnt = 1.f;
        out[g] = dot / cnt + bl3[0];
    }
}

extern "C" void kernel_launch(void* const* d_in, const int* in_sizes, int n_in,
                              void* d_out, int out_size, void* d_ws, size_t ws_size,
                              hipStream_t stream) {
    (void)n_in; (void)out_size; (void)ws_size;
    const float* nf    = (const float*)d_in[0];
    const int*   ei    = (const int*)d_in[1];
    const float* ea    = (const float*)d_in[2];
    const int*   batch = (const int*)d_in[3];
    const float* W_ne  = (const float*)d_in[4];
    const float* b_ne  = (const float*)d_in[5];
    const float* W_ee  = (const float*)d_in[6];
    const float* b_ee  = (const float*)d_in[7];
    const float* W_l3  = (const float*)d_in[8];
    const float* b_l3  = (const float*)d_in[9];
    const float *Wl[3], *asl[3], *adl[3], *Wel[3], *ael[3], *bbl[3];
    for (int l = 0; l < 3; ++l) {
        Wl[l]  = (const float*)d_in[10 + 6 * l];
        asl[l] = (const float*)d_in[11 + 6 * l];
        adl[l] = (const float*)d_in[12 + 6 * l];
        Wel[l] = (const float*)d_in[13 + 6 * l];
        ael[l] = (const float*)d_in[14 + 6 * l];
        bbl[l] = (const float*)d_in[15 + 6 * l];
    }

    const int n  = in_sizes[3];        // 100000
    const int e  = in_sizes[2] / 3;    // 1600000
    const int ep = e + n;
    const int*   ei0 = ei;
    const int*   ei1 = ei + e;

    char* w = (char*)d_ws;
    size_t off = 0;
    auto alloc = [&](size_t b) { size_t o = off; off = (off + b + 255) & ~(size_t)255; return o; };
    float* x0     = (float*)(w + alloc((size_t)n * 16 * 4));
    float* x1     = (float*)(w + alloc((size_t)n * 32 * 4));
    float* x2     = (float*)(w + alloc((size_t)n * 32 * 4));
    float* x3     = (float*)(w + alloc((size_t)n * 32 * 4));
    float* h      = (float*)(w + alloc((size_t)n * 32 * 4));
    float* asrc   = (float*)(w + alloc((size_t)n * 4));
    float* adst   = (float*)(w + alloc((size_t)n * 4));
    float* ef     = (float*)(w + alloc((size_t)e * 2 * 4));
    float* p      = (float*)(w + alloc((size_t)ep * 4));
    int*   deg    = (int*)(w + alloc((size_t)n * 4));
    int*   rp     = (int*)(w + alloc((size_t)(n + 1) * 4));
    int*   cursor = (int*)(w + alloc((size_t)n * 4));
    int*   aux    = (int*)(w + alloc(512 * 4));
    int*   sorted = (int*)(w + alloc((size_t)ep * 4));
    float* consts = (float*)(w + alloc(256));
    int*   bounds = (int*)(w + alloc(129 * 4));

    hipMemsetAsync(deg, 0, (size_t)n * 4, stream);
    hipMemsetAsync(consts, 0, 256, stream);

    k_node_enc<<<(n * 16 + 255) / 256, 256, 0, stream>>>(nf, W_ne, b_ne, x0, n);
    k_edge_enc<<<(e + 255) / 256, 256, 0, stream>>>(ea, W_ee, b_ee, ef, consts + 12, e);
    k_deg<<<(ep + 255) / 256, 256, 0, stream>>>(ei1, deg, e, n);
    int nb = (n + 255) / 256;
    k_scan1<<<nb, 256, 0, stream>>>(deg, rp, aux, n);
    k_scan2<<<1, 512, 0, stream>>>(aux, nb);
    k_scan3<<<nb, 256, 0, stream>>>(rp, aux, cursor, n, ep);
    k_scatter<<<(ep + 255) / 256, 256, 0, stream>>>(ei1, cursor, sorted, e, n);
    k_consts<<<1, 64, 0, stream>>>(Wel[0], ael[0], Wel[1], ael[1], Wel[2], ael[2],
                                   consts, 1.0f / (float)e);
    k_bounds<<<1, 256, 0, stream>>>(batch, bounds, n, 128);

    const float* xin = x0;
    float* xo[3] = {x1, x2, x3};
    for (int l = 0; l < 3; ++l) {
        if (l == 0)
            k_hproj<16><<<(n + 7) / 8, 256, 0, stream>>>(xin, Wl[l], asl[l], adl[l],
                                                         h, asrc, adst, n);
        else
            k_hproj<32><<<(n + 7) / 8, 256, 0, stream>>>(xin, Wl[l], asl[l], adl[l],
                                                         h, asrc, adst, n);
        k_edgep<<<(ep + 255) / 256, 256, 0, stream>>>(ei0, ei1, ef, asrc, adst,
                                                      consts, p, e, n, l);
        k_agg<<<(n + 7) / 8, 256, 0, stream>>>(ei0, rp, sorted, p, h, bbl[l], xo[l], e, n);
        xin = xo[l];
    }
    k_pool<<<128, 128, 0, stream>>>(x1, x2, x3, bounds, W_l3, b_l3, (float*)d_out);
}

// Round 2
// 706.821 us; speedup vs baseline: 1.8668x; 1.8668x over previous
//
#include <hip/hip_runtime.h>

// ---------------------------------------------------------------------------
// 3-layer GAT (heads=1) forward. N=100000, E=1600000, Ep=E+N, G=128,
// ND=16, ED=2, H=32.
// R2: CSR-ordered src/ef arrays (no eid indirection), edgep fused into agg
// with 4-wide gather ILP; pool replaced by node-parallel dot + atomics.
// ---------------------------------------------------------------------------

__global__ void k_node_enc(const float* __restrict__ nf, const float* __restrict__ W,
                           const float* __restrict__ b, float* __restrict__ x, int n) {
    int gid = blockIdx.x * 256 + threadIdx.x;
    if (gid >= n * 16) return;
    int node = gid >> 4, j = gid & 15;
    const float* xr = nf + node * 9;
    float acc = b[j];
#pragma unroll
    for (int k = 0; k < 9; ++k) acc += xr[k] * W[k * 16 + j];
    x[gid] = acc;
}

__global__ void k_edge_enc(const float* __restrict__ ea, const float* __restrict__ W,
                           const float* __restrict__ b, float* __restrict__ ef,
                           float* __restrict__ colsum, int e) {
    __shared__ float s0[256], s1[256];
    int gid = blockIdx.x * 256 + threadIdx.x;
    float f0 = 0.f, f1 = 0.f;
    if (gid < e) {
        const float* r = ea + (size_t)gid * 3;
        float a0 = r[0], a1 = r[1], a2 = r[2];
        f0 = a0 * W[0] + a1 * W[2] + a2 * W[4] + b[0];
        f1 = a0 * W[1] + a1 * W[3] + a2 * W[5] + b[1];
        ef[(size_t)gid * 2 + 0] = f0;
        ef[(size_t)gid * 2 + 1] = f1;
    }
    s0[threadIdx.x] = f0; s1[threadIdx.x] = f1;
    __syncthreads();
    for (int off = 128; off > 0; off >>= 1) {
        if (threadIdx.x < off) {
            s0[threadIdx.x] += s0[threadIdx.x + off];
            s1[threadIdx.x] += s1[threadIdx.x + off];
        }
        __syncthreads();
    }
    if (threadIdx.x == 0) { atomicAdd(colsum + 0, s0[0]); atomicAdd(colsum + 1, s1[0]); }
}

__global__ void k_deg(const int* __restrict__ dstE, int* __restrict__ deg, int e, int n) {
    int gid = blockIdx.x * 256 + threadIdx.x;
    if (gid >= e + n) return;
    int d = (gid < e) ? dstE[gid] : gid - e;
    atomicAdd(deg + d, 1);
}

__global__ void k_scan1(const int* __restrict__ deg, int* __restrict__ rp,
                        int* __restrict__ aux, int n) {
    __shared__ int s[256];
    int t = threadIdx.x, i = blockIdx.x * 256 + t;
    int v = (i < n) ? deg[i] : 0;
    s[t] = v; __syncthreads();
    for (int o = 1; o < 256; o <<= 1) {
        int x = (t >= o) ? s[t - o] : 0;
        __syncthreads();
        s[t] += x;
        __syncthreads();
    }
    if (i < n) rp[i] = s[t] - v;
    if (t == 255) aux[blockIdx.x] = s[255];
}

__global__ void k_scan2(int* __restrict__ aux, int nb) {
    __shared__ int s[512];
    int t = threadIdx.x;
    int v = (t < nb) ? aux[t] : 0;
    s[t] = v; __syncthreads();
    for (int o = 1; o < 512; o <<= 1) {
        int x = (t >= o) ? s[t - o] : 0;
        __syncthreads();
        s[t] += x;
        __syncthreads();
    }
    if (t < nb) aux[t] = s[t] - v;
}

__global__ void k_scan3(int* __restrict__ rp, const int* __restrict__ aux,
                        int* __restrict__ cursor, int n, int ep) {
    int i = blockIdx.x * 256 + threadIdx.x;
    if (i < n) {
        int v = rp[i] + aux[blockIdx.x];
        rp[i] = v;
        cursor[i] = v;
    }
    if (i == 0) rp[n] = ep;
}

// Scatter src + edge-feature pair (self-loop rows get the mean fill) into
// CSR position order. Removes all eid indirection from the per-layer loop.
__global__ void k_scatter(const int* __restrict__ ei0, const int* __restrict__ ei1,
                          const float2* __restrict__ ef, const float* __restrict__ consts,
                          float einv, int* __restrict__ cursor,
                          int* __restrict__ srcs, float2* __restrict__ efs,
                          int e, int n) {
    int gid = blockIdx.x * 256 + threadIdx.x;
    if (gid >= e + n) return;
    int s, d; float2 f;
    if (gid < e) {
        s = ei0[gid]; d = ei1[gid]; f = ef[gid];
    } else {
        s = d = gid - e;
        f = make_float2(consts[12] * einv, consts[13] * einv);
    }
    int pos = atomicAdd(cursor + d, 1);
    srcs[pos] = s;
    efs[pos] = f;
}

// consts: [0..5] = (We@ae) per layer (2 floats each), [12..13] = ef colsums
__global__ void k_consts(const float* __restrict__ We0, const float* __restrict__ ae0,
                         const float* __restrict__ We1, const float* __restrict__ ae1,
                         const float* __restrict__ We2, const float* __restrict__ ae2,
                         float* __restrict__ consts) {
    if (threadIdx.x != 0 || blockIdx.x != 0) return;
    const float* We[3] = {We0, We1, We2};
    const float* ae[3] = {ae0, ae1, ae2};
    for (int l = 0; l < 3; ++l) {
        float c0 = 0.f, c1 = 0.f;
        for (int j = 0; j < 32; ++j) {
            c0 += We[l][j] * ae[l][j];
            c1 += We[l][32 + j] * ae[l][j];
        }
        consts[l * 2 + 0] = c0;
        consts[l * 2 + 1] = c1;
    }
}

template <int K>
__global__ void k_hproj(const float* __restrict__ x, const float* __restrict__ W,
                        const float* __restrict__ as_, const float* __restrict__ ad_,
                        float* __restrict__ h, float* __restrict__ asrc,
                        float* __restrict__ adst, int n) {
    __shared__ float sW[K * 32];
    for (int i = threadIdx.x; i < K * 32; i += 256) sW[i] = W[i];
    __syncthreads();
    int node = blockIdx.x * 8 + (threadIdx.x >> 5);
    int j = threadIdx.x & 31;
    if (node >= n) return;
    const float* xr = x + (size_t)node * K;
    float acc = 0.f;
#pragma unroll
    for (int k = 0; k < K; ++k) acc += xr[k] * sW[k * 32 + j];
    h[(size_t)node * 32 + j] = acc;
    float r1 = acc * as_[j], r2 = acc * ad_[j];
    for (int off = 16; off > 0; off >>= 1) {
        r1 += __shfl_xor(r1, off, 32);
        r2 += __shfl_xor(r2, off, 32);
    }
    if (j == 0) { asrc[node] = r1; adst[node] = r2; }
}

// Fused edge-softmax + aggregation. One 32-lane group per dst node.
// Chunk of 32 edges: coalesced srcs/efs loads, inline p=exp(lrelu(...)),
// then shfl-broadcast loop (x4 unroll -> 4 h-gathers in flight).
__global__ void k_agg(const int* __restrict__ rp, const int* __restrict__ srcs,
                      const float2* __restrict__ efs, const float* __restrict__ asrc,
                      const float* __restrict__ adst, const float* __restrict__ consts,
                      const float* __restrict__ h, const float* __restrict__ bb,
                      float* __restrict__ xout, int n, int layer) {
    int node = blockIdx.x * 8 + (threadIdx.x >> 5);
    int j = threadIdx.x & 31;
    if (node >= n) return;
    float c0 = consts[layer * 2], c1 = consts[layer * 2 + 1];
    int r0 = rp[node], r1 = rp[node + 1];
    float adn = adst[node];
    float acc = 0.f, psum = 0.f;
    for (int c = r0; c < r1; c += 32) {
        int i = c + j;
        float pe = 0.f; int s = 0;
        if (i < r1) {
            s = srcs[i];
            float2 f = efs[i];
            float lg = asrc[s] + adn + f.x * c0 + f.y * c1;
            lg = lg > 0.f ? lg : 0.2f * lg;
            pe = __expf(lg);
        }
        psum += pe;
        int cnt = min(32, r1 - c);
        int t = 0;
        for (; t + 4 <= cnt; t += 4) {
            int s0 = __shfl(s, t, 32), s1 = __shfl(s, t + 1, 32);
            int s2 = __shfl(s, t + 2, 32), s3 = __shfl(s, t + 3, 32);
            float p0 = __shfl(pe, t, 32), p1 = __shfl(pe, t + 1, 32);
            float p2 = __shfl(pe, t + 2, 32), p3 = __shfl(pe, t + 3, 32);
            float h0 = h[(size_t)s0 * 32 + j];
            float h1 = h[(size_t)s1 * 32 + j];
            float h2 = h[(size_t)s2 * 32 + j];
            float h3 = h[(size_t)s3 * 32 + j];
            acc += p0 * h0; acc += p1 * h1; acc += p2 * h2; acc += p3 * h3;
        }
        for (; t < cnt; ++t) {
            int st = __shfl(s, t, 32);
            float pt = __shfl(pe, t, 32);
            acc += pt * h[(size_t)st * 32 + j];
        }
    }
    for (int off = 16; off > 0; off >>= 1) psum += __shfl_xor(psum, off, 32);
    xout[(size_t)node * 32 + j] = acc / (psum + 1e-16f) + bb[j];
}

__global__ void k_bounds(const int* __restrict__ batch, int* __restrict__ bounds,
                         int n, int g) {
    int t = blockIdx.x * 256 + threadIdx.x;
    if (t > g) return;
    if (t == g) { bounds[g] = n; return; }
    int lo = 0, hi = n;
    while (lo < hi) {
        int mid = (lo + hi) >> 1;
        if (batch[mid] < t) lo = mid + 1; else hi = mid;
    }
    bounds[t] = lo;
}

// out[g] = (1/cnt_g) * sum_{n in g} (x_cat[n] . W_l3) + b  -- commuted readout.
__global__ void k_dot(const float* __restrict__ x1, const float* __restrict__ x2,
                      const float* __restrict__ x3, const int* __restrict__ batch,
                      const float* __restrict__ Wl3, float* __restrict__ gsum, int n) {
    int node = blockIdx.x * 8 + (threadIdx.x >> 5);
    int j = threadIdx.x & 31;
    if (node >= n) return;
    size_t o = (size_t)node * 32 + j;
    float v = x1[o] * Wl3[j] + x2[o] * Wl3[32 + j] + x3[o] * Wl3[64 + j];
    for (int off = 16; off > 0; off >>= 1) v += __shfl_xor(v, off, 32);
    if (j == 0) atomicAdd(gsum + (size_t)batch[node] * 32 + (blockIdx.x & 31), v);
}

__global__ void k_out(const float* __restrict__ gsum, const int* __restrict__ bounds,
                      const float* __restrict__ bl3, float* __restrict__ out, int g) {
    int t = threadIdx.x;
    if (t >= g) return;
    float acc = 0.f;
    for (int k = 0; k < 32; ++k) acc += gsum[(size_t)t * 32 + k];
    float cnt = (float)(bounds[t + 1] - bounds[t]);
    out[t] = acc / fmaxf(cnt, 1.f) + bl3[0];
}

extern "C" void kernel_launch(void* const* d_in, const int* in_sizes, int n_in,
                              void* d_out, int out_size, void* d_ws, size_t ws_size,
                              hipStream_t stream) {
    (void)n_in; (void)out_size; (void)ws_size;
    const float* nf    = (const float*)d_in[0];
    const int*   ei    = (const int*)d_in[1];
    const float* ea    = (const float*)d_in[2];
    const int*   batch = (const int*)d_in[3];
    const float* W_ne  = (const float*)d_in[4];
    const float* b_ne  = (const float*)d_in[5];
    const float* W_ee  = (const float*)d_in[6];
    const float* b_ee  = (const float*)d_in[7];
    const float* W_l3  = (const float*)d_in[8];
    const float* b_l3  = (const float*)d_in[9];
    const float *Wl[3], *asl[3], *adl[3], *Wel[3], *ael[3], *bbl[3];
    for (int l = 0; l < 3; ++l) {
        Wl[l]  = (const float*)d_in[10 + 6 * l];
        asl[l] = (const float*)d_in[11 + 6 * l];
        adl[l] = (const float*)d_in[12 + 6 * l];
        Wel[l] = (const float*)d_in[13 + 6 * l];
        ael[l] = (const float*)d_in[14 + 6 * l];
        bbl[l] = (const float*)d_in[15 + 6 * l];
    }

    const int n  = in_sizes[3];        // 100000
    const int e  = in_sizes[2] / 3;    // 1600000
    const int ep = e + n;
    const int* ei0 = ei;
    const int* ei1 = ei + e;

    char* w = (char*)d_ws;
    size_t off = 0;
    auto alloc = [&](size_t b) { size_t o = off; off = (off + b + 255) & ~(size_t)255; return o; };
    float*  x0     = (float*)(w + alloc((size_t)n * 16 * 4));
    float*  x1     = (float*)(w + alloc((size_t)n * 32 * 4));
    float*  x2     = (float*)(w + alloc((size_t)n * 32 * 4));
    float*  x3     = (float*)(w + alloc((size_t)n * 32 * 4));
    float*  h      = (float*)(w + alloc((size_t)n * 32 * 4));
    float*  asrc   = (float*)(w + alloc((size_t)n * 4));
    float*  adst   = (float*)(w + alloc((size_t)n * 4));
    float*  ef     = (float*)(w + alloc((size_t)e * 2 * 4));
    int*    srcs   = (int*)(w + alloc((size_t)ep * 4));
    float2* efs    = (float2*)(w + alloc((size_t)ep * 8));
    int*    deg    = (int*)(w + alloc((size_t)n * 4));
    int*    rp     = (int*)(w + alloc((size_t)(n + 1) * 4));
    int*    cursor = (int*)(w + alloc((size_t)n * 4));
    int*    aux    = (int*)(w + alloc(512 * 4));
    float*  consts = (float*)(w + alloc(256));
    int*    bounds = (int*)(w + alloc(129 * 4));
    float*  gsum   = (float*)(w + alloc((size_t)128 * 32 * 4));

    hipMemsetAsync(deg, 0, (size_t)n * 4, stream);
    hipMemsetAsync(consts, 0, 256, stream);
    hipMemsetAsync(gsum, 0, (size_t)128 * 32 * 4, stream);

    k_node_enc<<<(n * 16 + 255) / 256, 256, 0, stream>>>(nf, W_ne, b_ne, x0, n);
    k_edge_enc<<<(e + 255) / 256, 256, 0, stream>>>(ea, W_ee, b_ee, ef, consts + 12, e);
    k_deg<<<(ep + 255) / 256, 256, 0, stream>>>(ei1, deg, e, n);
    int nb = (n + 255) / 256;
    k_scan1<<<nb, 256, 0, stream>>>(deg, rp, aux, n);
    k_scan2<<<1, 512, 0, stream>>>(aux, nb);
    k_scan3<<<nb, 256, 0, stream>>>(rp, aux, cursor, n, ep);
    k_scatter<<<(ep + 255) / 256, 256, 0, stream>>>(ei0, ei1, (const float2*)ef, consts,
                                                    1.0f / (float)e, cursor, srcs, efs, e, n);
    k_consts<<<1, 64, 0, stream>>>(Wel[0], ael[0], Wel[1], ael[1], Wel[2], ael[2], consts);
    k_bounds<<<1, 256, 0, stream>>>(batch, bounds, n, 128);

    const float* xin = x0;
    float* xo[3] = {x1, x2, x3};
    for (int l = 0; l < 3; ++l) {
        if (l == 0)
            k_hproj<16><<<(n + 7) / 8, 256, 0, stream>>>(xin, Wl[l], asl[l], adl[l],
                                                         h, asrc, adst, n);
        else
            k_hproj<32><<<(n + 7) / 8, 256, 0, stream>>>(xin, Wl[l], asl[l], adl[l],
                                                         h, asrc, adst, n);
        k_agg<<<(n + 7) / 8, 256, 0, stream>>>(rp, srcs, efs, asrc, adst, consts,
                                               h, bbl[l], xo[l], n, l);
        xin = xo[l];
    }
    k_dot<<<(n + 7) / 8, 256, 0, stream>>>(x1, x2, x3, batch, W_l3, gsum, n);
    k_out<<<1, 128, 0, stream>>>(gsum, bounds, b_l3, (float*)d_out, 128);
}